// Round 9
// baseline (198.058 us; speedup 1.0000x reference)
//
#include <hip/hip_runtime.h>
#include <hip/hip_bf16.h>

// CausalMultiHeadSelfAttention  B=2 S=2048 D_MODEL=1024 H=16 DH=64
// Pipeline: cast->bf16 (k-permuted) | GEMM1 (2-phase dbuf, unrolled x2) |
//           rope+pack | MFMA flash attn (unrolled x2, ones-MFMA lsum) | GEMM2

#define S_LEN 2048
#define DMODEL 1024
#define NH 16
#define QKVN 3072

typedef __attribute__((ext_vector_type(4))) short short4v;
typedef __attribute__((ext_vector_type(8))) short short8v;
typedef __attribute__((ext_vector_type(4))) float floatx4;

#define CSOFT 0.18033688f   // 0.125 * log2(e): folded into Q at pack time

__device__ __forceinline__ unsigned short f2bf(float f) {
  unsigned int u = __float_as_uint(f);
  u += 0x7FFFu + ((u >> 16) & 1u);
  return (unsigned short)(u >> 16);
}
__device__ __forceinline__ float bf2f(unsigned short u) {
  return __uint_as_float(((unsigned int)u) << 16);
}
__device__ __forceinline__ void gload16(const void* g, void* l) {
  __builtin_amdgcn_global_load_lds((const __attribute__((address_space(1))) void*)g,
                                   (__attribute__((address_space(3))) void*)l,
                                   16, 0, 0);
}
// ushort4-group c (4 logical elems) -> offset within 64-elem span, permuted
__device__ __forceinline__ int perm4(int c) {
  return (c >> 3) * 32 + (c & 3) * 8 + ((c >> 2) & 1) * 4;
}

// ---------------- fp32 -> bf16 cast with k-block permutation ----------------
__global__ __launch_bounds__(256) void cast_bf16_perm_k(const float* __restrict__ in,
                                                        unsigned short* __restrict__ out,
                                                        int nchunk) {
  int i = blockIdx.x * 256 + threadIdx.x;
  if (i >= nchunk) return;
  int c = i & 3;
  const float4* f4 = reinterpret_cast<const float4*>(in);
  float4 lo = f4[(i >> 2) * 8 + c];
  float4 hi = f4[(i >> 2) * 8 + 4 + c];
  short8v o;
  o[0] = (short)f2bf(lo.x); o[1] = (short)f2bf(lo.y);
  o[2] = (short)f2bf(lo.z); o[3] = (short)f2bf(lo.w);
  o[4] = (short)f2bf(hi.x); o[5] = (short)f2bf(hi.y);
  o[6] = (short)f2bf(hi.z); o[7] = (short)f2bf(hi.w);
  reinterpret_cast<short8v*>(out)[i] = o;
}

// ---------------- bf16 MFMA GEMM: C[M,N] = A[M,K]*B[N,K]^T (A,B k-permuted) ----------------
// 2-phase dbuf, kt-loop unrolled x2 so LDS buffer index is compile-time.
// LDS slot swizzle: chunk c of LDS-row r stored at slot (c + (r>>1))&3.
template <bool OUT_BF16>
__global__ __launch_bounds__(256) void gemm_bt(const unsigned short* __restrict__ A,
                                               const unsigned short* __restrict__ Bm,
                                               void* __restrict__ Cp, int M, int N, int K) {
  __shared__ __align__(16) unsigned short As[2][128 * 32];
  __shared__ __align__(16) unsigned short Bs[2][128 * 32];
  const int tid = threadIdx.x;
  const int lane = tid & 63;
  const int w = tid >> 6;
  const int wm = w >> 1, wn = w & 1;
  const int l15 = lane & 15, l4 = lane >> 4;
  const int bm = blockIdx.y * 128, bn = blockIdx.x * 128;
  const int srow = lane >> 2;
  const int schunk = ((lane & 3) - ((lane >> 3) & 3)) & 3;
  const int rslot = (l4 + (l15 >> 1)) & 3;

  floatx4 acc[4][4] = {};
  const int nt = K >> 5;   // assumed even (K=1024)

#define GSTAGE(T, BUF)                                                                   \
  {                                                                                      \
    const int k0s = (T) << 5;                                                            \
    _Pragma("unroll") for (int j = 0; j < 2; ++j) {                                      \
      const unsigned short* ga =                                                         \
          A + (size_t)(bm + j * 64 + w * 16 + srow) * K + k0s + schunk * 8;              \
      gload16(ga, &As[BUF][j * 2048 + w * 512]);                                         \
      const unsigned short* gb =                                                         \
          Bm + (size_t)(bn + j * 64 + w * 16 + srow) * K + k0s + schunk * 8;             \
      gload16(gb, &Bs[BUF][j * 2048 + w * 512]);                                         \
    }                                                                                    \
  }

#define GBODY(T, BUF)                                                                    \
  {                                                                                      \
    if ((T) + 1 < nt) {                                                                  \
      GSTAGE((T) + 1, BUF ^ 1);                                                          \
      asm volatile("s_waitcnt vmcnt(4)" ::: "memory");                                   \
    } else {                                                                             \
      asm volatile("s_waitcnt vmcnt(0)" ::: "memory");                                   \
    }                                                                                    \
    __syncthreads();                                                                     \
    short8v af[4], bfr[4];                                                               \
    _Pragma("unroll") for (int f = 0; f < 4; ++f) {                                      \
      af[f]  = *(const short8v*)(&As[BUF][(wm * 64 + f * 16 + l15) * 32 + rslot * 8]);   \
      bfr[f] = *(const short8v*)(&Bs[BUF][(wn * 64 + f * 16 + l15) * 32 + rslot * 8]);   \
    }                                                                                    \
    _Pragma("unroll") for (int f = 0; f < 4; ++f)                                        \
      _Pragma("unroll") for (int g = 0; g < 4; ++g)                                      \
        acc[f][g] = __builtin_amdgcn_mfma_f32_16x16x32_bf16(af[f], bfr[g], acc[f][g], 0, 0, 0); \
    __syncthreads();                                                                     \
  }

  GSTAGE(0, 0);
  for (int t = 0; t < nt; t += 2) {
    GBODY(t, 0);
    GBODY(t + 1, 1);
  }
#undef GBODY
#undef GSTAGE

#pragma unroll
  for (int f = 0; f < 4; ++f)
#pragma unroll
    for (int g = 0; g < 4; ++g)
#pragma unroll
      for (int r = 0; r < 4; ++r) {
        int row = bm + wm * 64 + f * 16 + l4 * 4 + r;
        int col = bn + wn * 64 + g * 16 + l15;
        if (OUT_BF16)
          ((unsigned short*)Cp)[(size_t)row * N + col] = f2bf(acc[f][g][r]);
        else
          ((float*)Cp)[(size_t)row * N + col] = acc[f][g][r];
      }
}

// ---------------- rope + pack ----------------
// Q pre-scaled by CSOFT; Q/K/vT written with chunk permutation (perm4).
__global__ __launch_bounds__(256) void rope_pack_k(const unsigned short* __restrict__ qkvb,
                                                   unsigned short* __restrict__ qp_,
                                                   unsigned short* __restrict__ kp_,
                                                   unsigned short* __restrict__ vtp_,
                                                   const float* __restrict__ cosp,
                                                   const float* __restrict__ sinp,
                                                   const int* __restrict__ tpos) {
  __shared__ unsigned short Vs[64][68];
  const int tid = threadIdx.x;
  const int bh = blockIdx.x >> 5;
  const int st = blockIdx.x & 31;
  const int b = bh >> 4, h = bh & 15;
  const int c = tid & 15, t0 = tid >> 4;
  const int s0 = st * 64;
  const int pc = perm4(c);

#pragma unroll
  for (int it = 0; it < 4; ++it) {
    const int tl = it * 16 + t0;
    const int s = s0 + tl;
    const int tp = tpos[s];
    const size_t base = ((size_t)(b * S_LEN + s)) * QKVN + h * 64 + c * 4;
    const float co0 = cosp[tp * 32 + 2 * c], si0 = sinp[tp * 32 + 2 * c];
    const float co1 = cosp[tp * 32 + 2 * c + 1], si1 = sinp[tp * 32 + 2 * c + 1];
    // Q (scaled), permuted store
    {
      const float c0 = co0 * CSOFT, s0q = si0 * CSOFT;
      const float c1 = co1 * CSOFT, s1q = si1 * CSOFT;
      ushort4 rv = *(const ushort4*)(qkvb + base);
      float a0 = bf2f(rv.x), a1 = bf2f(rv.y), a2 = bf2f(rv.z), a3 = bf2f(rv.w);
      ushort4 ov;
      ov.x = f2bf(a0 * c0 - a1 * s0q); ov.y = f2bf(a0 * s0q + a1 * c0);
      ov.z = f2bf(a2 * c1 - a3 * s1q); ov.w = f2bf(a2 * s1q + a3 * c1);
      *(ushort4*)(qp_ + ((size_t)bh * S_LEN + s) * 64 + pc) = ov;
    }
    // K, permuted store
    {
      ushort4 rv = *(const ushort4*)(qkvb + base + DMODEL);
      float a0 = bf2f(rv.x), a1 = bf2f(rv.y), a2 = bf2f(rv.z), a3 = bf2f(rv.w);
      ushort4 ov;
      ov.x = f2bf(a0 * co0 - a1 * si0); ov.y = f2bf(a0 * si0 + a1 * co0);
      ov.z = f2bf(a2 * co1 - a3 * si1); ov.w = f2bf(a2 * si1 + a3 * co1);
      *(ushort4*)(kp_ + ((size_t)bh * S_LEN + s) * 64 + pc) = ov;
    }
    // V -> LDS
    {
      ushort4 rv = *(const ushort4*)(qkvb + base + 2 * DMODEL);
      *(ushort4*)(&Vs[tl][c * 4]) = rv;
    }
  }
  __syncthreads();
#pragma unroll
  for (int it = 0; it < 4; ++it) {
    const int d = it * 16 + t0;
    ushort4 ov;
    ov.x = Vs[c * 4 + 0][d]; ov.y = Vs[c * 4 + 1][d];
    ov.z = Vs[c * 4 + 2][d]; ov.w = Vs[c * 4 + 3][d];
    *(ushort4*)(vtp_ + ((size_t)bh * 64 + d) * S_LEN + s0 + pc) = ov;
  }
}

// ---------------- MFMA flash attention ----------------
// LDS tile [64][64] bf16 (128B rows); stored chunk cc at slot cc^(row&7).
__device__ __forceinline__ short8v readfrag128(const unsigned short* L, int row, int cc) {
  return *(const short8v*)(L + row * 64 + (((cc) ^ (row & 7)) << 3));
}

__device__ __forceinline__ void stage_tiles(const unsigned short* kg0, const unsigned short* vg0,
                                            int kt, unsigned short* Kb, unsigned short* Vb,
                                            int tid, int w) {
#pragma unroll
  for (int i = 0; i < 2; ++i) {
    int jj = i * 256 + tid;
    int row = jj >> 3;
    int cc = (jj & 7) ^ (row & 7);
    gload16(kg0 + (size_t)kt * 4096 + row * 64 + cc * 8, Kb + (i * 256 + w * 64) * 8);
    gload16(vg0 + (size_t)row * S_LEN + kt * 64 + cc * 8, Vb + (i * 256 + w * 64) * 8);
  }
}

__global__ __launch_bounds__(256) void attn_mfma(const unsigned short* __restrict__ qp_,
                                                 const unsigned short* __restrict__ kp_,
                                                 const unsigned short* __restrict__ vtp_,
                                                 unsigned short* __restrict__ yb) {
  __shared__ __align__(16) unsigned short Kl[2][4096];
  __shared__ __align__(16) unsigned short Vl[2][4096];
  const int tid = threadIdx.x;
  const int lane = tid & 63, w = tid >> 6;
  const int l15 = lane & 15, l4 = lane >> 4;
  // 1024 blocks: XCD j&7 gets bh in {x, x+8, x+16, x+24}; big q-tiles first
  const int j = blockIdx.x;
  const int bh = (j & 7) + 8 * ((j >> 3) & 3);
  const int qt = 31 - (j >> 5);
  const int b = bh >> 4, h = bh & 15;

  const unsigned short* kg0 = kp_ + (size_t)bh * S_LEN * 64;
  const unsigned short* vg0 = vtp_ + (size_t)bh * 64 * S_LEN;

  // Q fragments (registers), chunk-permuted global: one 16B load per frag
  const unsigned short* qp = qp_ + ((size_t)bh * S_LEN + qt * 64 + w * 16 + l15) * 64;
  short8v qf[2];
#pragma unroll
  for (int c2 = 0; c2 < 2; ++c2)
    qf[c2] = *(const short8v*)(qp + c2 * 32 + l4 * 8);

  const short8v ones8 = {(short)0x3F80, (short)0x3F80, (short)0x3F80, (short)0x3F80,
                         (short)0x3F80, (short)0x3F80, (short)0x3F80, (short)0x3F80};

  floatx4 o[4] = {};
  floatx4 ls = {0.f, 0.f, 0.f, 0.f};   // row-sums via ones-MFMA, q = l4*4+r space
  float mrun = -1e30f;

#define ATTN_BODY(KT, BUF)                                                             \
  {                                                                                    \
    const int kt_ = (KT);                                                              \
    if (kt_ < qt) {                                                                    \
      stage_tiles(kg0, vg0, kt_ + 1, Kl[BUF ^ 1], Vl[BUF ^ 1], tid, w);                \
      asm volatile("s_waitcnt vmcnt(4)" ::: "memory");                                 \
    } else {                                                                           \
      asm volatile("s_waitcnt vmcnt(0)" ::: "memory");                                 \
    }                                                                                  \
    __syncthreads();                                                                   \
    const bool diag = (kt_ == qt);                                                     \
    float s_[4][4];                                                                    \
    __builtin_amdgcn_s_setprio(1);                                                     \
    _Pragma("unroll") for (int g = 0; g < 4; ++g) {                                    \
      if (diag && g > w) {                                                             \
        s_[g][0] = s_[g][1] = s_[g][2] = s_[g][3] = -INFINITY;                         \
        continue;                                                                      \
      }                                                                                \
      short8v k0 = readfrag128(Kl[BUF], g * 16 + l15, l4);                             \
      short8v k1 = readfrag128(Kl[BUF], g * 16 + l15, 4 + l4);                         \
      floatx4 t = {0.f, 0.f, 0.f, 0.f};                                                \
      t = __builtin_amdgcn_mfma_f32_16x16x32_bf16(k0, qf[0], t, 0, 0, 0);              \
      t = __builtin_amdgcn_mfma_f32_16x16x32_bf16(k1, qf[1], t, 0, 0, 0);              \
      _Pragma("unroll") for (int r = 0; r < 4; ++r) {                                  \
        float v = t[r];                                                                \
        if (diag && g == w && (l4 * 4 + r > l15)) v = -INFINITY;                       \
        s_[g][r] = v;                                                                  \
      }                                                                                \
    }                                                                                  \
    __builtin_amdgcn_s_setprio(0);                                                     \
    float tm = fmaxf(fmaxf(s_[0][0], s_[0][1]), s_[0][2]);                             \
    tm = fmaxf(fmaxf(tm, s_[0][3]), s_[1][0]);                                         \
    tm = fmaxf(fmaxf(tm, s_[1][1]), s_[1][2]);                                         \
    tm = fmaxf(fmaxf(tm, s_[1][3]), s_[2][0]);                                         \
    tm = fmaxf(fmaxf(tm, s_[2][1]), s_[2][2]);                                         \
    tm = fmaxf(fmaxf(tm, s_[2][3]), s_[3][0]);                                         \
    tm = fmaxf(fmaxf(tm, s_[3][1]), s_[3][2]);                                         \
    tm = fmaxf(tm, s_[3][3]);                                                          \
    tm = fmaxf(tm, __shfl_xor(tm, 16));                                                \
    tm = fmaxf(tm, __shfl_xor(tm, 32));                                                \
    if (!__all(tm <= mrun + 8.0f)) {                                                   \
      float nm = fmaxf(mrun, tm);                                                      \
      float rs = exp2f(mrun - nm);                                                     \
      mrun = nm;                                                                       \
      float rsr[4];                                                                    \
      _Pragma("unroll") for (int r = 0; r < 4; ++r) rsr[r] = __shfl(rs, l4 * 4 + r);   \
      _Pragma("unroll") for (int r = 0; r < 4; ++r) ls[r] *= rsr[r];                   \
      _Pragma("unroll") for (int dt = 0; dt < 4; ++dt)                                 \
        _Pragma("unroll") for (int r = 0; r < 4; ++r) o[dt][r] *= rsr[r];              \
    }                                                                                  \
    union { unsigned short u[16]; short8v v[2]; } pk;                                  \
    _Pragma("unroll") for (int g = 0; g < 4; ++g)                                      \
      _Pragma("unroll") for (int r = 0; r < 4; ++r) {                                  \
        float p = exp2f(s_[g][r] - mrun);                                              \
        pk.u[g * 4 + r] = (unsigned short)(__float_as_uint(p) >> 16);                  \
      }                                                                                \
    __builtin_amdgcn_s_setprio(1);                                                     \
    ls = __builtin_amdgcn_mfma_f32_16x16x32_bf16(pk.v[0], ones8, ls, 0, 0, 0);         \
    ls = __builtin_amdgcn_mfma_f32_16x16x32_bf16(pk.v[1], ones8, ls, 0, 0, 0);         \
    _Pragma("unroll") for (int dt = 0; dt < 4; ++dt) {                                 \
      short8v v0 = readfrag128(Vl[BUF], dt * 16 + l15, l4);                            \
      short8v v1 = readfrag128(Vl[BUF], dt * 16 + l15, 4 + l4);                        \
      o[dt] = __builtin_amdgcn_mfma_f32_16x16x32_bf16(pk.v[0], v0, o[dt], 0, 0, 0);    \
      o[dt] = __builtin_amdgcn_mfma_f32_16x16x32_bf16(pk.v[1], v1, o[dt], 0, 0, 0);    \
    }                                                                                  \
    __builtin_amdgcn_s_setprio(0);                                                     \
    __syncthreads();                                                                   \
  }

  stage_tiles(kg0, vg0, 0, Kl[0], Vl[0], tid, w);   // prologue
  int kt = 0;
  for (; kt + 1 <= qt; kt += 2) {
    ATTN_BODY(kt, 0);
    ATTN_BODY(kt + 1, 1);
  }
  if (kt <= qt) ATTN_BODY(kt, 0);
#undef ATTN_BODY

  float linv[4];
#pragma unroll
  for (int r = 0; r < 4; ++r) linv[r] = 1.f / ls[r];
  // yb store, k-permuted columns for GEMM2's A operand
#pragma unroll
  for (int dt = 0; dt < 4; ++dt)
#pragma unroll
    for (int r = 0; r < 4; ++r) {
      size_t row = (size_t)(b * S_LEN + qt * 64 + w * 16 + l4 * 4 + r);
      int col = (h * 2 + (dt >> 1)) * 32 + (l15 >> 2) * 8 + (l15 & 3) + 4 * (dt & 1);
      yb[row * DMODEL + col] = f2bf(o[dt][r] * linv[r]);
    }
}

// ---------------- launch ----------------
extern "C" void kernel_launch(void* const* d_in, const int* in_sizes, int n_in,
                              void* d_out, int out_size, void* d_ws, size_t ws_size,
                              hipStream_t stream) {
  const float* x     = (const float*)d_in[0];
  const float* wqkv  = (const float*)d_in[1];
  const float* w_out = (const float*)d_in[2];
  const float* cosp  = (const float*)d_in[3];
  const float* sinp  = (const float*)d_in[4];
  const int*   tpos  = (const int*)d_in[5];
  float* out = (float*)d_out;
  char* ws = (char*)d_ws;

  const size_t MB = 1024 * 1024;
  unsigned short* xb    = (unsigned short*)(ws + 0);        // 8 MB
  unsigned short* wqkvb = (unsigned short*)(ws + 8 * MB);   // 6 MB
  unsigned short* wob   = (unsigned short*)(ws + 14 * MB);  // 2 MB
  unsigned short* qkvb  = (unsigned short*)(ws + 16 * MB);  // 24 MB
  unsigned short* qpk   = (unsigned short*)(ws + 40 * MB);  // 8 MB
  unsigned short* kpk   = (unsigned short*)(ws + 48 * MB);  // 8 MB
  unsigned short* vtpk  = (unsigned short*)(ws + 56 * MB);  // 8 MB
  unsigned short* yb    = (unsigned short*)(ws + 0);        // 8 MB (reuse xb)

  cast_bf16_perm_k<<<2048, 256, 0, stream>>>(x, xb, 524288);
  cast_bf16_perm_k<<<1536, 256, 0, stream>>>(wqkv, wqkvb, 393216);
  cast_bf16_perm_k<<<512, 256, 0, stream>>>(w_out, wob, 131072);

  gemm_bt<true><<<dim3(24, 32), 256, 0, stream>>>(xb, wqkvb, qkvb, 4096, QKVN, 1024);

  rope_pack_k<<<1024, 256, 0, stream>>>(qkvb, qpk, kpk, vtpk, cosp, sinp, tpos);

  attn_mfma<<<1024, 256, 0, stream>>>(qpk, kpk, vtpk, yb);

  gemm_bt<false><<<dim3(8, 32), 256, 0, stream>>>(yb, wob, out, 4096, DMODEL, 1024);
}